// Round 5
// baseline (401.223 us; speedup 1.0000x reference)
//
#include <hip/hip_runtime.h>
#include <cstddef>
#include <cstdint>

#define BZd   128
#define Td    32
#define Dd    768
#define DFFd  3072
#define Ed    8
#define NBEAM 256
#define ROWS_TOT 8192
#define OUT_ELEMS 6291456
#define MAXTILES 72

typedef unsigned short u16;
typedef __attribute__((ext_vector_type(4))) unsigned short ushort4v;
typedef __attribute__((ext_vector_type(8))) short frag_ab;
typedef __attribute__((ext_vector_type(4))) float floatx4;

__device__ __forceinline__ u16 f2bf(float f) {
  unsigned int u = __builtin_bit_cast(unsigned int, f);
  u += 0x7FFFu + ((u >> 16) & 1u);
  return (u16)(u >> 16);
}

__device__ __forceinline__ void async_copy16(u16* lds, const u16* g) {
  __builtin_amdgcn_global_load_lds(
      (const __attribute__((address_space(1))) void*)g,
      (__attribute__((address_space(3))) void*)lds, 16, 0, 0);
}

// fast gelu (tanh form via sigmoid): max abs err ~3e-4, << 0.14 threshold
__device__ __forceinline__ float gelu_fast(float x) {
  float z = 1.5957691216f * (x + 0.044715f * x * x * x);
  return x / (1.0f + __expf(-z));
}

// ---------------------------------------------------------------------------
// Routing + x conversion fused. Phase 1 is byte-identical routing math to
// rounds 2-4 (near-tie softmax — do not perturb accumulation order).
// Phase 2 converts this batch's x slab to bf16 (slab is L1/L2-hot).
// ---------------------------------------------------------------------------
__global__ __launch_bounds__(256) void route_convert_kernel(
    const float* __restrict__ x, const float* __restrict__ Wg,
    float* __restrict__ out, int* __restrict__ sel, u16* __restrict__ xbf) {
  int b = blockIdx.x;
  int t = threadIdx.x;
  __shared__ float red[256][8];
  float la[8];
#pragma unroll
  for (int e = 0; e < 8; e++) la[e] = 0.f;
  for (int d = t; d < Dd; d += 256) {
    const float* xp = x + (size_t)b * Td * Dd + d;
    float xa = 0.f;
#pragma unroll
    for (int tt = 0; tt < Td; tt++) xa += xp[(size_t)tt * Dd];
    xa *= (1.0f / 32.0f);
#pragma unroll
    for (int e = 0; e < 8; e++) la[e] += xa * Wg[d * 8 + e];
  }
#pragma unroll
  for (int e = 0; e < 8; e++) red[t][e] = la[e];
  __syncthreads();
  for (int s = 128; s > 0; s >>= 1) {
    if (t < s) {
#pragma unroll
      for (int e = 0; e < 8; e++) red[t][e] += red[t + s][e];
    }
    __syncthreads();
  }
  if (t == 0) {
    float lg[8];
#pragma unroll
    for (int e = 0; e < 8; e++) lg[e] = red[0][e];
    float mx = lg[0];
#pragma unroll
    for (int e = 1; e < 8; e++) mx = fmaxf(mx, lg[e]);
    float p[8];
    float sum = 0.f;
#pragma unroll
    for (int e = 0; e < 8; e++) { p[e] = __expf(lg[e] - mx); sum += p[e]; }
    float inv = 1.0f / sum;
#pragma unroll
    for (int e = 0; e < 8; e++) p[e] *= inv;
    int i0 = 0; float v0 = p[0];
#pragma unroll
    for (int e = 1; e < 8; e++) if (p[e] > v0) { v0 = p[e]; i0 = e; }
    int i1 = -1; float v1 = -1.0f;
#pragma unroll
    for (int e = 0; e < 8; e++) if (e != i0 && p[e] > v1) { v1 = p[e]; i1 = e; }
    float* bs = out + OUT_ELEMS;
    float* er = out + OUT_ELEMS + NBEAM;
    bs[2 * b] = v0; bs[2 * b + 1] = v1;
    er[2 * b] = (float)i0; er[2 * b + 1] = (float)i1;
    sel[2 * b] = i0; sel[2 * b + 1] = i1;
  }
  // phase 2: bf16 conversion of this batch's slab (32*768 floats, L2-hot)
  const float* xp = x + (size_t)b * Td * Dd;
  u16* op = xbf + (size_t)b * Td * Dd;
#pragma unroll
  for (int k = 0; k < 24; k++) {
    int flat = (k * 256 + t) * 4;
    float4 v = *(const float4*)(xp + flat);
    ushort4v pv = {f2bf(v.x), f2bf(v.y), f2bf(v.z), f2bf(v.w)};
    *(ushort4v*)(op + flat) = pv;
  }
}

// ---------------------------------------------------------------------------
// Bucket: group beams by expert; perm fill parallelized across 8 threads.
// ---------------------------------------------------------------------------
__global__ __launch_bounds__(256) void bucket_kernel(
    const int* __restrict__ sel, int* __restrict__ perm, int4* __restrict__ tiles) {
  __shared__ int ssel[NBEAM];
  __shared__ int scnt[8];
  __shared__ int soff[8];
  __shared__ int sperm[NBEAM];
  int t = threadIdx.x;
  ssel[t] = sel[t];
  __syncthreads();
  if (t == 0) {
    for (int e = 0; e < 8; e++) scnt[e] = 0;
    for (int n = 0; n < NBEAM; n++) scnt[ssel[n]]++;
    int o = 0;
    for (int e = 0; e < 8; e++) { soff[e] = o; o += scnt[e]; }
  }
  __syncthreads();
  if (t < 8) {
    int idx = soff[t];
    for (int n = 0; n < NBEAM; n++)
      if (ssel[n] == t) sperm[idx++] = n;
  }
  if (t == 0) {
    int tt = 0;
    for (int e = 0; e < 8; e++) {
      int nr = scnt[e] * 32;
      int base = soff[e] * 32;
      for (int r0 = 0; r0 < nr; r0 += 128) {
        tiles[tt] = make_int4(e, base + r0, min(128, nr - r0), 0);
        tt++;
      }
    }
    for (; tt < MAXTILES; tt++) tiles[tt] = make_int4(-1, 0, 0, 0);
  }
  __syncthreads();
  perm[t] = sperm[t];
}

// ---------------------------------------------------------------------------
// Unified weight transpose + fp32->bf16. z<8: W1 expert z; z>=8: W2.
//   w1t[e][f][d] = W1[e][d][f0+f]    (rows d: blockIdx.x, cols f: blockIdx.y)
//   w2t[e][d][f] = W2[e][f0+f][d]    (rows f: blockIdx.y, cols d: blockIdx.x)
// ---------------------------------------------------------------------------
__global__ __launch_bounds__(256) void transpose_all_kernel(
    const float* __restrict__ W1, u16* __restrict__ w1t,
    const float* __restrict__ W2, u16* __restrict__ w2t, int f0, int FC) {
  __shared__ u16 tile[64][65];
  int z = blockIdx.z, bx = blockIdx.x, by = blockIdx.y;
  int t = threadIdx.x;
  const float* ip; u16* op; int ld_in, ld_out;
  if (z < 8) {
    int e = z;
    ld_in = DFFd; ld_out = Dd;
    ip = W1 + (size_t)e * Dd * DFFd + (size_t)(bx * 64) * DFFd + (f0 + by * 64);
    op = w1t + (size_t)e * FC * Dd + (size_t)(by * 64) * Dd + bx * 64;
  } else {
    int e = z - 8;
    ld_in = Dd; ld_out = FC;
    ip = W2 + (size_t)e * DFFd * Dd + (size_t)(f0 + by * 64) * Dd + bx * 64;
    op = w2t + (size_t)e * Dd * FC + (size_t)(bx * 64) * FC + by * 64;
  }
  int rr = t >> 4, cc4 = (t & 15) * 4;
#pragma unroll
  for (int i = 0; i < 4; i++) {
    int r = rr + 16 * i;
    float4 v = *(const float4*)(ip + (size_t)r * ld_in + cc4);
    tile[r][cc4 + 0] = f2bf(v.x);
    tile[r][cc4 + 1] = f2bf(v.y);
    tile[r][cc4 + 2] = f2bf(v.z);
    tile[r][cc4 + 3] = f2bf(v.w);
  }
  __syncthreads();
  int ccw = t >> 4, r4 = (t & 15) * 4;
#pragma unroll
  for (int i = 0; i < 4; i++) {
    int cc = ccw + 16 * i;
    ushort4v pv = {tile[r4 + 0][cc], tile[r4 + 1][cc], tile[r4 + 2][cc], tile[r4 + 3][cc]};
    *(ushort4v*)(op + (size_t)cc * ld_out + r4) = pv;
  }
}

// ---------------------------------------------------------------------------
// GEMM1: h = gelu(X @ W1T^T + b1). BK=32, DOUBLE-BUFFERED LDS (2x16KB=32KB):
// loads for iter i+1 issued right after iter i's single barrier, so the
// vmcnt(0) drain at the next barrier waits on loads with a full iteration
// (16 MFMA + 8 ds_read) of cover. One barrier per iter.
// XOR chunk-swizzle (c ^ (row>>1)&3) -> 2-way banks (free, m136).
// ---------------------------------------------------------------------------
__global__ __launch_bounds__(256) void gemm1_kernel(
    const u16* __restrict__ xbf, const u16* __restrict__ w1t,
    const float* __restrict__ b1, const int* __restrict__ perm,
    const int4* __restrict__ tiles, u16* __restrict__ h, int f0, int FC) {
  int4 meta = tiles[blockIdx.y];
  int e = meta.x;
  if (e < 0) return;
  int grow0 = meta.y, nrows = meta.z;
  int bx = blockIdx.x;

  __shared__ __align__(16) u16 As[2][128 * 32];
  __shared__ __align__(16) u16 Bs[2][128 * 32];

  int t = threadIdx.x;
  int l = t & 63, w = t >> 6;
  int wm = w & 1, wn = w >> 1;
  int lrow = l & 15, lquad = l >> 4;

  // staging: slot s = j*256+t covers row m=s>>2, swizzled chunk (s&3)^((m>>1)&3)
  const u16* ag[2]; const u16* bg[2];
  int lbase[2];
#pragma unroll
  for (int j = 0; j < 2; j++) {
    int s = j * 256 + t;
    int m = s >> 2;
    int koff = ((s & 3) ^ ((m >> 1) & 3)) * 8;
    int bidx = (grow0 >> 5) + (m >> 5);
    bidx = bidx < NBEAM ? bidx : NBEAM - 1;
    int batch = perm[bidx] >> 1;
    ag[j] = xbf + ((size_t)batch * Td + (m & 31)) * Dd + koff;
    bg[j] = w1t + ((size_t)e * FC + bx * 128 + m) * Dd + koff;
    lbase[j] = (j * 256 + w * 64) * 8;   // wave-uniform LDS slot base (u16)
  }

  int aoff[4], boff[4];
#pragma unroll
  for (int i = 0; i < 4; i++) {
    int ra = wm * 64 + i * 16 + lrow;
    aoff[i] = ra * 32 + ((lquad ^ ((ra >> 1) & 3)) * 8);
    int rb = wn * 64 + i * 16 + lrow;
    boff[i] = rb * 32 + ((lquad ^ ((rb >> 1) & 3)) * 8);
  }

  floatx4 acc[4][4];
#pragma unroll
  for (int mi = 0; mi < 4; mi++)
#pragma unroll
    for (int ni = 0; ni < 4; ni++) acc[mi][ni] = (floatx4){0.f, 0.f, 0.f, 0.f};

  // prologue: issue k-tile 0 into buffer 0
#pragma unroll
  for (int j = 0; j < 2; j++) {
    async_copy16(&As[0][lbase[j]], ag[j]);
    async_copy16(&Bs[0][lbase[j]], bg[j]);
    ag[j] += 32; bg[j] += 32;
  }

  const int NIT = Dd / 32;   // 24
  for (int it = 0; it < NIT; ++it) {
    __syncthreads();          // drains my buf[cur] loads; all waves past it-1 reads
    int cur = it & 1, nxt = cur ^ 1;
    if (it + 1 < NIT) {
#pragma unroll
      for (int j = 0; j < 2; j++) {
        async_copy16(&As[nxt][lbase[j]], ag[j]);
        async_copy16(&Bs[nxt][lbase[j]], bg[j]);
        ag[j] += 32; bg[j] += 32;
      }
    }
    frag_ab af[4], bf[4];
#pragma unroll
    for (int mi = 0; mi < 4; mi++) af[mi] = *(const frag_ab*)(&As[cur][aoff[mi]]);
#pragma unroll
    for (int ni = 0; ni < 4; ni++) bf[ni] = *(const frag_ab*)(&Bs[cur][boff[ni]]);
#pragma unroll
    for (int mi = 0; mi < 4; mi++)
#pragma unroll
      for (int ni = 0; ni < 4; ni++)
        acc[mi][ni] = __builtin_amdgcn_mfma_f32_16x16x32_bf16(af[mi], bf[ni], acc[mi][ni], 0, 0, 0);
  }

  int f_base = bx * 128;
#pragma unroll
  for (int mi = 0; mi < 4; mi++) {
    int row0 = wm * 64 + mi * 16 + lquad * 4;
#pragma unroll
    for (int ni = 0; ni < 4; ni++) {
      int col = wn * 64 + ni * 16 + lrow;
      float bias = b1[(size_t)e * DFFd + f0 + f_base + col];
#pragma unroll
      for (int r = 0; r < 4; r++) {
        int row = row0 + r;
        if (row < nrows) {
          float vv = acc[mi][ni][r] + bias;
          h[(size_t)(grow0 + row) * FC + f_base + col] = f2bf(gelu_fast(vv));
        }
      }
    }
  }
}

// ---------------------------------------------------------------------------
// GEMM2: out = h @ W2T^T + b2. Same double-buffered pipeline. No atomics.
// ---------------------------------------------------------------------------
__global__ __launch_bounds__(256) void gemm2_kernel(
    const u16* __restrict__ h, const u16* __restrict__ w2t,
    const float* __restrict__ b2, const int* __restrict__ perm,
    const int4* __restrict__ tiles, float* __restrict__ out,
    int FC, int first) {
  int4 meta = tiles[blockIdx.y];
  int e = meta.x;
  if (e < 0) return;
  int grow0 = meta.y, nrows = meta.z;
  int bx = blockIdx.x;

  __shared__ __align__(16) u16 As[2][128 * 32];
  __shared__ __align__(16) u16 Bs[2][128 * 32];
  __shared__ int sbeam[4];

  int t = threadIdx.x;
  if (t < 4) {
    int idx = (grow0 >> 5) + t;
    sbeam[t] = perm[idx < NBEAM ? idx : NBEAM - 1];
  }
  int l = t & 63, w = t >> 6;
  int wm = w & 1, wn = w >> 1;
  int lrow = l & 15, lquad = l >> 4;

  const u16* ag[2]; const u16* bg[2];
  int lbase[2];
#pragma unroll
  for (int j = 0; j < 2; j++) {
    int s = j * 256 + t;
    int m = s >> 2;
    int koff = ((s & 3) ^ ((m >> 1) & 3)) * 8;
    int arow = grow0 + m;
    arow = arow < ROWS_TOT ? arow : ROWS_TOT - 1;
    ag[j] = h + (size_t)arow * FC + koff;
    bg[j] = w2t + ((size_t)e * Dd + bx * 128 + m) * FC + koff;
    lbase[j] = (j * 256 + w * 64) * 8;
  }

  int aoff[4], boff[4];
#pragma unroll
  for (int i = 0; i < 4; i++) {
    int ra = wm * 64 + i * 16 + lrow;
    aoff[i] = ra * 32 + ((lquad ^ ((ra >> 1) & 3)) * 8);
    int rb = wn * 64 + i * 16 + lrow;
    boff[i] = rb * 32 + ((lquad ^ ((rb >> 1) & 3)) * 8);
  }

  floatx4 acc[4][4];
#pragma unroll
  for (int mi = 0; mi < 4; mi++)
#pragma unroll
    for (int ni = 0; ni < 4; ni++) acc[mi][ni] = (floatx4){0.f, 0.f, 0.f, 0.f};

#pragma unroll
  for (int j = 0; j < 2; j++) {
    async_copy16(&As[0][lbase[j]], ag[j]);
    async_copy16(&Bs[0][lbase[j]], bg[j]);
    ag[j] += 32; bg[j] += 32;
  }

  const int NIT_ = FC / 32;
  for (int it = 0; it < NIT_; ++it) {
    __syncthreads();
    int cur = it & 1, nxt = cur ^ 1;
    if (it + 1 < NIT_) {
#pragma unroll
      for (int j = 0; j < 2; j++) {
        async_copy16(&As[nxt][lbase[j]], ag[j]);
        async_copy16(&Bs[nxt][lbase[j]], bg[j]);
        ag[j] += 32; bg[j] += 32;
      }
    }
    frag_ab af[4], bf[4];
#pragma unroll
    for (int mi = 0; mi < 4; mi++) af[mi] = *(const frag_ab*)(&As[cur][aoff[mi]]);
#pragma unroll
    for (int ni = 0; ni < 4; ni++) bf[ni] = *(const frag_ab*)(&Bs[cur][boff[ni]]);
#pragma unroll
    for (int mi = 0; mi < 4; mi++)
#pragma unroll
      for (int ni = 0; ni < 4; ni++)
        acc[mi][ni] = __builtin_amdgcn_mfma_f32_16x16x32_bf16(af[mi], bf[ni], acc[mi][ni], 0, 0, 0);
  }

#pragma unroll
  for (int mi = 0; mi < 4; mi++) {
    int row0 = wm * 64 + mi * 16 + lquad * 4;
#pragma unroll
    for (int ni = 0; ni < 4; ni++) {
      int col = wn * 64 + ni * 16 + lrow;
      int dg = bx * 128 + col;
      float bias = b2[(size_t)e * Dd + dg];
#pragma unroll
      for (int r = 0; r < 4; r++) {
        int row = row0 + r;
        if (row < nrows) {
          int beam = sbeam[row >> 5];
          size_t o = ((size_t)beam * Td + (row & 31)) * Dd + dg;
          if (first) out[o] = acc[mi][ni][r] + bias;
          else out[o] += acc[mi][ni][r];
        }
      }
    }
  }
}

// ---------------------------------------------------------------------------
extern "C" void kernel_launch(void* const* d_in, const int* in_sizes, int n_in,
                              void* d_out, int out_size, void* d_ws, size_t ws_size,
                              hipStream_t stream) {
  const float* x  = (const float*)d_in[0];
  const float* Wg = (const float*)d_in[2];
  const float* W1 = (const float*)d_in[3];
  const float* b1 = (const float*)d_in[4];
  const float* W2 = (const float*)d_in[5];
  const float* b2 = (const float*)d_in[6];
  float* out = (float*)d_out;

  char* ws = (char*)d_ws;
  int*  sel   = (int*)ws;
  int*  perm  = sel + NBEAM;
  int4* tiles = (int4*)(ws + 4096);

  const size_t xbf_off = 65536;
  const size_t xbf_bytes = (size_t)BZd * Td * Dd * 2;
  int FC = 384;
  if      (xbf_off + xbf_bytes + (size_t)40960 * 3072 <= ws_size) FC = 3072;
  else if (xbf_off + xbf_bytes + (size_t)40960 * 1536 <= ws_size) FC = 1536;
  else if (xbf_off + xbf_bytes + (size_t)40960 * 768  <= ws_size) FC = 768;
  int NC = DFFd / FC;

  u16* xbf = (u16*)(ws + xbf_off);
  u16* w1t = (u16*)(ws + xbf_off + xbf_bytes);
  u16* w2t = w1t + (size_t)Ed * FC * Dd;
  u16* h   = w2t + (size_t)Ed * Dd * FC;

  route_convert_kernel<<<BZd, 256, 0, stream>>>(x, Wg, out, sel, xbf);
  bucket_kernel<<<1, 256, 0, stream>>>(sel, perm, tiles);

  for (int c = 0; c < NC; c++) {
    transpose_all_kernel<<<dim3(Dd / 64, FC / 64, 16), 256, 0, stream>>>(
        W1, w1t, W2, w2t, c * FC, FC);
    gemm1_kernel<<<dim3(FC / 128, MAXTILES), 256, 0, stream>>>(
        xbf, w1t, b1, perm, tiles, h, c * FC, FC);
    gemm2_kernel<<<dim3(Dd / 128, MAXTILES), 256, 0, stream>>>(
        h, w2t, b2, perm, tiles, out, FC, c == 0 ? 1 : 0);
  }
}